// Round 9
// baseline (109.420 us; speedup 1.0000x reference)
//
#include <hip/hip_runtime.h>

// SparsePropMaxPool closed form (verified rounds 1-7, absmax=0):
//   ori_map_h[b,h,s,e] = max(x[b,h,s..e]) if (s, d=e-s) in SET else 0
//   SET: d in [0,15] any s | d odd in [17,31], s even | d%4==3 in [35,63], s%4==0
//   props_h[b,p,h] = max(x[b,h, s_p .. s_p+d_p])  (153 constant ranges)
//   mask[b,0,s,e] = 1 at SET positions
// Out layout: props (64*153*512) | map (64*512*64*64) | mask (64*64*64)
//
// R6=101.5us (nt, 4x256B per wave-store). R7 A/B: plain=104.8 -> nt confirmed.
// R8 (1KB-contiguous wave stores) had a units bug: store offset sb*1024 FLOATS
// (=4KB) instead of sb*256 floats (=1KB). R9 = R8 with the one-line fix.
// Map: each wave owns one bh row; per iteration stores 4 consecutive s-rows
// (64 lanes x f4 = contiguous 1KB). Recurrence: per-row width-1..4 max tables
// W0..W3 (shfl-built, wave-private LDS, no __syncthreads): reset (d<=3) reads
// W[d][s]; extension v = max(v, W3[s]).

#define B_ 64
#define H_ 512
#define N_ 64
#define NPROP 153

typedef float f4 __attribute__((ext_vector_type(4)));

__device__ __forceinline__ bool in_set(int s, int d) {
    if (d < 0) return false;
    if (d <= 15) return true;
    if (d <= 31) return (d & 1) && ((s & 1) == 0);        // d=17,19..31 odd, s even
    return (d >= 35) && ((d & 3) == 3) && ((s & 3) == 0); // d=35,39..63, s%4==0
}

__global__ __launch_bounds__(256) void fused_kernel(const float* __restrict__ x,
                                                    float* __restrict__ out_props,
                                                    float* __restrict__ out_map,
                                                    float* __restrict__ out_mask) {
    const int tid = threadIdx.x;    // 0..255
    const int bid = blockIdx.x;     // 0..8255

    if (bid < B_) {
        // ---------------- props + mask block: one batch b (R6 code) ----------
        const int b = bid;

        f4* mk = reinterpret_cast<f4*>(out_mask + (size_t)b * (N_ * N_));
        #pragma unroll
        for (int i = 0; i < 4; ++i) {
            const int idx = tid + 256 * i;   // f4 index; s = idx>>4, c = idx&15
            const int s = idx >> 4, c = idx & 15;
            f4 w;
            w.x = in_set(s, 4 * c + 0 - s) ? 1.f : 0.f;
            w.y = in_set(s, 4 * c + 1 - s) ? 1.f : 0.f;
            w.z = in_set(s, 4 * c + 2 - s) ? 1.f : 0.f;
            w.w = in_set(s, 4 * c + 3 - s) ? 1.f : 0.f;
            __builtin_nontemporal_store(w, &mk[idx]);
        }

        #pragma unroll 1
        for (int half = 0; half < 2; ++half) {
            const int h = tid + 256 * half;
            const f4* xr = reinterpret_cast<const f4*>(x + ((size_t)b * H_ + h) * N_);
            float r[64];
            #pragma unroll
            for (int k = 0; k < 16; ++k) {
                f4 v = xr[k];
                r[4*k+0] = v.x; r[4*k+1] = v.y; r[4*k+2] = v.z; r[4*k+3] = v.w;
            }
            float a[63];
            #pragma unroll
            for (int i = 0; i < 63; ++i) a[i] = fmaxf(r[i], r[i+1]);
            float m4[61];
            #pragma unroll
            for (int i = 0; i < 61; ++i) m4[i] = fmaxf(a[i], a[i+2]);
            float T3[57];                    // T3[i] = max(x[i..i+7])
            #pragma unroll
            for (int i = 0; i < 57; ++i) T3[i] = fmaxf(m4[i], m4[i+4]);

            float* po = out_props + (size_t)b * NPROP * H_ + h;
            int p = 0;
            #pragma unroll
            for (int s = 0; s < 57; ++s)              // d=7
                __builtin_nontemporal_store(T3[s], &po[(size_t)(p++) * H_]);
            #pragma unroll
            for (int s = 0; s < 49; ++s)              // d=15
                __builtin_nontemporal_store(fmaxf(T3[s], T3[s + 8]),
                                            &po[(size_t)(p++) * H_]);
            #pragma unroll
            for (int s = 0; s <= 40; s += 2)          // d=23
                __builtin_nontemporal_store(fmaxf(fmaxf(T3[s], T3[s + 8]), T3[s + 16]),
                                            &po[(size_t)(p++) * H_]);
            #pragma unroll
            for (int s = 0; s <= 32; s += 2)          // d=31
                __builtin_nontemporal_store(
                    fmaxf(fmaxf(T3[s], T3[s + 8]), fmaxf(T3[s + 16], T3[s + 24])),
                    &po[(size_t)(p++) * H_]);
            #pragma unroll
            for (int s = 0; s <= 16; s += 4) {        // d=47
                float m = T3[s];
                #pragma unroll
                for (int j = 8; j <= 40; j += 8) m = fmaxf(m, T3[s + j]);
                __builtin_nontemporal_store(m, &po[(size_t)(p++) * H_]);
            }
            #pragma unroll
            for (int s = 0; s <= 8; s += 4) {         // d=55
                float m = T3[s];
                #pragma unroll
                for (int j = 8; j <= 48; j += 8) m = fmaxf(m, T3[s + j]);
                __builtin_nontemporal_store(m, &po[(size_t)(p++) * H_]);
            }
            {                                         // d=63
                float m = T3[0];
                #pragma unroll
                for (int j = 8; j <= 56; j += 8) m = fmaxf(m, T3[j]);
                __builtin_nontemporal_store(m, &po[(size_t)p * H_]);
            }
        }
        return;
    }

    // -------- map: wave owns one bh row; 16 x contiguous-1KB nt stores --------
    const int mb = bid - B_;            // 0..8191
    const int w  = tid >> 6;            // wave 0..3
    const int l  = tid & 63;
    const size_t bh = (size_t)mb * 4 + w;

    // wave-private width-{1,2,3,4} sliding-max tables; no __syncthreads needed
    // (DS ops are in-order within a wave). Pitch 68: banks (4r+s)%32 distinct.
    __shared__ float W[4][4][68];

    const float xv = x[bh * N_ + l];
    const float x1 = __shfl_down(xv, 1);
    const float w1 = fmaxf(xv, x1);            // width2 @ l (junk l=63: never read)
    const float x2 = __shfl_down(xv, 2);
    const float w2 = fmaxf(w1, x2);            // width3 (junk l>=62: never read)
    const float w12 = __shfl_down(w1, 2);
    const float w3 = fmaxf(w1, w12);           // width4 (junk l>=61: never read)
    W[w][0][l] = xv; W[w][1][l] = w1; W[w][2][l] = w2; W[w][3][l] = w3;

    const int j = l >> 4;               // sub-row 0..3
    const int t = l & 15;               // f4 column 0..15
    float* orow = out_map + bh * (size_t)(N_ * N_) + (size_t)l * 4;

    float vrun[4] = {0.f, 0.f, 0.f, 0.f};
    #pragma unroll
    for (int sb = 15; sb >= 0; --sb) {  // s decreasing: window extends left by 4
        const int s = 4 * sb + j;
        float oo[4];
        #pragma unroll
        for (int c = 0; c < 4; ++c) {
            const int e = 4 * t + c;
            const int d = e - s;                       // first nonneg d is in [0,3]
            const int rr = d < 0 ? 0 : (d > 3 ? 3 : d);
            const float tv = W[w][rr][s];              // reset value / W3 extension
            const float nv = (d <= 3) ? tv : fmaxf(vrun[c], tv);
            vrun[c] = nv;
            oo[c] = in_set(s, d) ? nv : 0.f;
        }
        f4 o = {oo[0], oo[1], oo[2], oo[3]};
        // rows s=4sb..4sb+3 = floats [sb*256, sb*256+255]; lane adds l*4 (R8 bug:
        // was sb*1024 floats -> 4x stride, OOB scatter)
        __builtin_nontemporal_store(o, reinterpret_cast<f4*>(orow + sb * 256));
    }
}

extern "C" void kernel_launch(void* const* d_in, const int* in_sizes, int n_in,
                              void* d_out, int out_size, void* d_ws, size_t ws_size,
                              hipStream_t stream) {
    const float* x = (const float*)d_in[0];   // (64, 512, 64) f32
    float* out       = (float*)d_out;
    float* out_props = out;                                   // 5,013,504
    float* out_map   = out + (size_t)B_ * NPROP * H_;         // 134,217,728
    float* out_mask  = out_map + (size_t)B_ * H_ * N_ * N_;   // 262,144

    fused_kernel<<<dim3(B_ + B_ * H_ / 4), dim3(256), 0, stream>>>(
        x, out_props, out_map, out_mask);
}

// Round 10
// 105.583 us; speedup vs baseline: 1.0363x; 1.0363x over previous
//
#include <hip/hip_runtime.h>

// SparsePropMaxPool closed form (verified rounds 1-9, absmax=0):
//   ori_map_h[b,h,s,e] = max(x[b,h,s..e]) if (s, d=e-s) in SET else 0
//   SET: d in [0,15] any s | d odd in [17,31], s even | d%4==3 in [35,63], s%4==0
//   props_h[b,p,h] = max(x[b,h, s_p .. s_p+d_p])  (153 constant ranges)
//   mask[b,0,s,e] = 1 at SET positions
// Out layout: props (64*153*512) | map (64*512*64*64) | mask (64*64*64)
//
// History: R6 best=101.5us (nt, 16-row map blocks, 64 coarse props blocks).
// R7: plain stores 104.8 -> nt confirmed. R9: 1KB-contig wave stores 109.4 ->
// contiguity refuted. R10 theory: remaining gap is SCHEDULING TAIL — 8.25
// 10us-map-blocks/CU means +1-block stragglers cost ~8us. Fix = granularity:
// uniform 128-thr blocks; map = 4096 blocks x 8 rows (16/CU), props = 256
// blocks (1/4 batch, one h per thread, ~1.5us) packed into gaps. Code inside
// each path is frozen R6 logic.

#define B_ 64
#define H_ 512
#define N_ 64
#define NPROP 153

typedef float f4 __attribute__((ext_vector_type(4)));

__device__ __forceinline__ bool in_set(int s, int d) {
    if (d < 0) return false;
    if (d <= 15) return true;
    if (d <= 31) return (d & 1) && ((s & 1) == 0);        // d=17,19..31 odd, s even
    return (d >= 35) && ((d & 3) == 3) && ((s & 3) == 0); // d=35,39..63, s%4==0
}

#define NPROPBLK 256   // 4 per batch

__global__ __launch_bounds__(128) void fused_kernel(const float* __restrict__ x,
                                                    float* __restrict__ out_props,
                                                    float* __restrict__ out_map,
                                                    float* __restrict__ out_mask) {
    const int tid = threadIdx.x;    // 0..127
    const int bid = blockIdx.x;     // 0..4351

    if (bid < NPROPBLK) {
        // ------------- props block: batch b, quarter q (128 h rows) -------------
        const int b = bid >> 2;
        const int q = bid & 3;
        const int h = q * 128 + tid;

        const f4* xr = reinterpret_cast<const f4*>(x + ((size_t)b * H_ + h) * N_);
        float r[64];
        #pragma unroll
        for (int k = 0; k < 16; ++k) {
            f4 v = xr[k];
            r[4*k+0] = v.x; r[4*k+1] = v.y; r[4*k+2] = v.z; r[4*k+3] = v.w;
        }
        float a[63];
        #pragma unroll
        for (int i = 0; i < 63; ++i) a[i] = fmaxf(r[i], r[i+1]);
        float m4[61];
        #pragma unroll
        for (int i = 0; i < 61; ++i) m4[i] = fmaxf(a[i], a[i+2]);
        float T3[57];                    // T3[i] = max(x[i..i+7])
        #pragma unroll
        for (int i = 0; i < 57; ++i) T3[i] = fmaxf(m4[i], m4[i+4]);

        float* po = out_props + (size_t)b * NPROP * H_ + h;
        int p = 0;
        #pragma unroll
        for (int s = 0; s < 57; ++s)              // d=7
            __builtin_nontemporal_store(T3[s], &po[(size_t)(p++) * H_]);
        #pragma unroll
        for (int s = 0; s < 49; ++s)              // d=15
            __builtin_nontemporal_store(fmaxf(T3[s], T3[s + 8]),
                                        &po[(size_t)(p++) * H_]);
        #pragma unroll
        for (int s = 0; s <= 40; s += 2)          // d=23
            __builtin_nontemporal_store(fmaxf(fmaxf(T3[s], T3[s + 8]), T3[s + 16]),
                                        &po[(size_t)(p++) * H_]);
        #pragma unroll
        for (int s = 0; s <= 32; s += 2)          // d=31
            __builtin_nontemporal_store(
                fmaxf(fmaxf(T3[s], T3[s + 8]), fmaxf(T3[s + 16], T3[s + 24])),
                &po[(size_t)(p++) * H_]);
        #pragma unroll
        for (int s = 0; s <= 16; s += 4) {        // d=47
            float m = T3[s];
            #pragma unroll
            for (int j = 8; j <= 40; j += 8) m = fmaxf(m, T3[s + j]);
            __builtin_nontemporal_store(m, &po[(size_t)(p++) * H_]);
        }
        #pragma unroll
        for (int s = 0; s <= 8; s += 4) {         // d=55
            float m = T3[s];
            #pragma unroll
            for (int j = 8; j <= 48; j += 8) m = fmaxf(m, T3[s + j]);
            __builtin_nontemporal_store(m, &po[(size_t)(p++) * H_]);
        }
        {                                         // d=63
            float m = T3[0];
            #pragma unroll
            for (int j = 8; j <= 56; j += 8) m = fmaxf(m, T3[j]);
            __builtin_nontemporal_store(m, &po[(size_t)p * H_]);
        }

        if (q == 0) {   // mask for batch b: 1024 f4, 8 per thread
            f4* mk = reinterpret_cast<f4*>(out_mask + (size_t)b * (N_ * N_));
            #pragma unroll
            for (int i = 0; i < 8; ++i) {
                const int idx = tid + 128 * i;   // f4 index; s = idx>>4, c = idx&15
                const int s = idx >> 4, c = idx & 15;
                f4 w;
                w.x = in_set(s, 4 * c + 0 - s) ? 1.f : 0.f;
                w.y = in_set(s, 4 * c + 1 - s) ? 1.f : 0.f;
                w.z = in_set(s, 4 * c + 2 - s) ? 1.f : 0.f;
                w.w = in_set(s, 4 * c + 3 - s) ? 1.f : 0.f;
                __builtin_nontemporal_store(w, &mk[idx]);
            }
        }
        return;
    }

    // -------- map block: 8 bh-rows, nt float4 stores (frozen R6 inner loop) ----
    const int mb = bid - NPROPBLK;      // 0..4095
    const int g  = tid >> 4;            // row within block 0..7
    const int t  = tid & 15;            // float4 column 0..15
    const size_t bh = (size_t)mb * 8 + g;

    __shared__ __align__(16) float xs[8][72];   // 288B pitch: conflict-free
    f4 xv = reinterpret_cast<const f4*>(x)[mb * 128 + tid];
    *reinterpret_cast<f4*>(&xs[g][4 * t]) = xv;
    __syncthreads();

    f4* mrow = reinterpret_cast<f4*>(out_map + bh * (size_t)(N_ * N_));
    const int e0 = 4 * t;
    float vx = 0.f, vy = 0.f, vz = 0.f, vw = 0.f;
    #pragma unroll
    for (int s = N_ - 1; s >= 0; --s) {   // v_j = max(x[s..e_j]), reset at s==e_j
        const float mv = xs[g][s];
        vx = (s == e0 + 0) ? mv : fmaxf(vx, mv);
        vy = (s == e0 + 1) ? mv : fmaxf(vy, mv);
        vz = (s == e0 + 2) ? mv : fmaxf(vz, mv);
        vw = (s == e0 + 3) ? mv : fmaxf(vw, mv);
        f4 w;
        w.x = in_set(s, e0 + 0 - s) ? vx : 0.f;   // s compile-time -> t-compares
        w.y = in_set(s, e0 + 1 - s) ? vy : 0.f;
        w.z = in_set(s, e0 + 2 - s) ? vz : 0.f;
        w.w = in_set(s, e0 + 3 - s) ? vw : 0.f;
        __builtin_nontemporal_store(w, &mrow[s * 16 + t]);
    }
}

extern "C" void kernel_launch(void* const* d_in, const int* in_sizes, int n_in,
                              void* d_out, int out_size, void* d_ws, size_t ws_size,
                              hipStream_t stream) {
    const float* x = (const float*)d_in[0];   // (64, 512, 64) f32
    float* out       = (float*)d_out;
    float* out_props = out;                                   // 5,013,504
    float* out_map   = out + (size_t)B_ * NPROP * H_;         // 134,217,728
    float* out_mask  = out_map + (size_t)B_ * H_ * N_ * N_;   // 262,144

    fused_kernel<<<dim3(NPROPBLK + B_ * H_ / 8), dim3(128), 0, stream>>>(
        x, out_props, out_map, out_mask);
}

// Round 11
// 102.756 us; speedup vs baseline: 1.0649x; 1.0275x over previous
//
#include <hip/hip_runtime.h>

// SparsePropMaxPool closed form (verified rounds 1-10, absmax=0):
//   ori_map_h[b,h,s,e] = max(x[b,h,s..e]) if (s, d=e-s) in SET else 0
//   SET: d in [0,15] any s | d odd in [17,31], s even | d%4==3 in [35,63], s%4==0
//   props_h[b,p,h] = max(x[b,h, s_p .. s_p+d_p])  (153 constant ranges)
//   mask[b,0,s,e] = 1 at SET positions
// Out layout: props (64*153*512) | map (64*512*64*64) | mask (64*64*64)
//
// History: R6 best=101.5us (nt stores, 2048x256thr map blocks, 64 props blocks).
// R7 plain=104.8 (nt confirmed). R9 contig-1KB=109.4 (refuted). R10 fine-grain
// =105.6 (tail theory refuted). R11: map blocks are co-resident (VGPR 52), so
// the 5.6-vs-6.76TB/s gap is stream geometry, not tail: fill runs ~3.4 waves/CU
// with long grid-stride streams; R6 ran 32 streams/CU. R11 = fill-shaped map:
// 512 blocks (2/CU) x 4 sequential 16-row groups, barrier-free (each wave reads
// only the LDS rows it wrote: g=tid>>4 partitions by wave), register prefetch
// of next group's x during the store loop. Inner loop frozen R6.

#define B_ 64
#define H_ 512
#define N_ 64
#define NPROP 153
#define MAPBLK 512
#define NGRP 2048            // 16-row groups total
#define GRP_PER_BLK (NGRP / MAPBLK)

typedef float f4 __attribute__((ext_vector_type(4)));

__device__ __forceinline__ bool in_set(int s, int d) {
    if (d < 0) return false;
    if (d <= 15) return true;
    if (d <= 31) return (d & 1) && ((s & 1) == 0);        // d=17,19..31 odd, s even
    return (d >= 35) && ((d & 3) == 3) && ((s & 3) == 0); // d=35,39..63, s%4==0
}

__global__ __launch_bounds__(256) void fused_kernel(const float* __restrict__ x,
                                                    float* __restrict__ out_props,
                                                    float* __restrict__ out_map,
                                                    float* __restrict__ out_mask) {
    const int tid = threadIdx.x;    // 0..255
    const int bid = blockIdx.x;     // 0..575

    if (bid < B_) {
        // ---------------- props + mask block: one batch b (frozen R6) ----------
        const int b = bid;

        f4* mk = reinterpret_cast<f4*>(out_mask + (size_t)b * (N_ * N_));
        #pragma unroll
        for (int i = 0; i < 4; ++i) {
            const int idx = tid + 256 * i;   // f4 index; s = idx>>4, c = idx&15
            const int s = idx >> 4, c = idx & 15;
            f4 w;
            w.x = in_set(s, 4 * c + 0 - s) ? 1.f : 0.f;
            w.y = in_set(s, 4 * c + 1 - s) ? 1.f : 0.f;
            w.z = in_set(s, 4 * c + 2 - s) ? 1.f : 0.f;
            w.w = in_set(s, 4 * c + 3 - s) ? 1.f : 0.f;
            __builtin_nontemporal_store(w, &mk[idx]);
        }

        #pragma unroll 1
        for (int half = 0; half < 2; ++half) {
            const int h = tid + 256 * half;
            const f4* xr = reinterpret_cast<const f4*>(x + ((size_t)b * H_ + h) * N_);
            float r[64];
            #pragma unroll
            for (int k = 0; k < 16; ++k) {
                f4 v = xr[k];
                r[4*k+0] = v.x; r[4*k+1] = v.y; r[4*k+2] = v.z; r[4*k+3] = v.w;
            }
            float a[63];
            #pragma unroll
            for (int i = 0; i < 63; ++i) a[i] = fmaxf(r[i], r[i+1]);
            float m4[61];
            #pragma unroll
            for (int i = 0; i < 61; ++i) m4[i] = fmaxf(a[i], a[i+2]);
            float T3[57];                    // T3[i] = max(x[i..i+7])
            #pragma unroll
            for (int i = 0; i < 57; ++i) T3[i] = fmaxf(m4[i], m4[i+4]);

            float* po = out_props + (size_t)b * NPROP * H_ + h;
            int p = 0;
            #pragma unroll
            for (int s = 0; s < 57; ++s)              // d=7
                __builtin_nontemporal_store(T3[s], &po[(size_t)(p++) * H_]);
            #pragma unroll
            for (int s = 0; s < 49; ++s)              // d=15
                __builtin_nontemporal_store(fmaxf(T3[s], T3[s + 8]),
                                            &po[(size_t)(p++) * H_]);
            #pragma unroll
            for (int s = 0; s <= 40; s += 2)          // d=23
                __builtin_nontemporal_store(fmaxf(fmaxf(T3[s], T3[s + 8]), T3[s + 16]),
                                            &po[(size_t)(p++) * H_]);
            #pragma unroll
            for (int s = 0; s <= 32; s += 2)          // d=31
                __builtin_nontemporal_store(
                    fmaxf(fmaxf(T3[s], T3[s + 8]), fmaxf(T3[s + 16], T3[s + 24])),
                    &po[(size_t)(p++) * H_]);
            #pragma unroll
            for (int s = 0; s <= 16; s += 4) {        // d=47
                float m = T3[s];
                #pragma unroll
                for (int j = 8; j <= 40; j += 8) m = fmaxf(m, T3[s + j]);
                __builtin_nontemporal_store(m, &po[(size_t)(p++) * H_]);
            }
            #pragma unroll
            for (int s = 0; s <= 8; s += 4) {         // d=55
                float m = T3[s];
                #pragma unroll
                for (int j = 8; j <= 48; j += 8) m = fmaxf(m, T3[s + j]);
                __builtin_nontemporal_store(m, &po[(size_t)(p++) * H_]);
            }
            {                                         // d=63
                float m = T3[0];
                #pragma unroll
                for (int j = 8; j <= 56; j += 8) m = fmaxf(m, T3[j]);
                __builtin_nontemporal_store(m, &po[(size_t)p * H_]);
            }
        }
        return;
    }

    // -------- map: 512 blocks x 4 grid-stride groups of 16 rows, barrier-free --
    const int mb = bid - B_;            // 0..511
    const int g  = tid >> 4;            // row within group 0..15 (wave-partitioned)
    const int t  = tid & 15;            // float4 column 0..15
    const int e0 = 4 * t;

    // Double-buffered, wave-private (wave w touches rows 4w..4w+3 only) -> no
    // __syncthreads anywhere. 288B row pitch: xs[.][g][s] 4 distinct banks/wave.
    __shared__ __align__(16) float xs[2][16][72];

    f4 cur = reinterpret_cast<const f4*>(x)[mb * 256 + tid];   // group 0
    int buf = 0;

    #pragma unroll 1
    for (int i = 0; i < GRP_PER_BLK; ++i) {
        const int grp = mb + MAPBLK * i;
        *reinterpret_cast<f4*>(&xs[buf][g][e0]) = cur;
        if (i < GRP_PER_BLK - 1)   // prefetch next group during store loop
            cur = reinterpret_cast<const f4*>(x)[(mb + MAPBLK * (i + 1)) * 256 + tid];

        const size_t bh = (size_t)grp * 16 + g;
        f4* mrow = reinterpret_cast<f4*>(out_map + bh * (size_t)(N_ * N_));
        float vx = 0.f, vy = 0.f, vz = 0.f, vw = 0.f;
        #pragma unroll
        for (int s = N_ - 1; s >= 0; --s) {   // v_j = max(x[s..e_j]), reset s==e_j
            const float mv = xs[buf][g][s];
            vx = (s == e0 + 0) ? mv : fmaxf(vx, mv);
            vy = (s == e0 + 1) ? mv : fmaxf(vy, mv);
            vz = (s == e0 + 2) ? mv : fmaxf(vz, mv);
            vw = (s == e0 + 3) ? mv : fmaxf(vw, mv);
            f4 w;
            w.x = in_set(s, e0 + 0 - s) ? vx : 0.f;   // s compile-time -> t-compares
            w.y = in_set(s, e0 + 1 - s) ? vy : 0.f;
            w.z = in_set(s, e0 + 2 - s) ? vz : 0.f;
            w.w = in_set(s, e0 + 3 - s) ? vw : 0.f;
            __builtin_nontemporal_store(w, &mrow[s * 16 + t]);
        }
        buf ^= 1;
    }
}

extern "C" void kernel_launch(void* const* d_in, const int* in_sizes, int n_in,
                              void* d_out, int out_size, void* d_ws, size_t ws_size,
                              hipStream_t stream) {
    const float* x = (const float*)d_in[0];   // (64, 512, 64) f32
    float* out       = (float*)d_out;
    float* out_props = out;                                   // 5,013,504
    float* out_map   = out + (size_t)B_ * NPROP * H_;         // 134,217,728
    float* out_mask  = out_map + (size_t)B_ * H_ * N_ * N_;   // 262,144

    fused_kernel<<<dim3(B_ + MAPBLK), dim3(256), 0, stream>>>(
        x, out_props, out_map, out_mask);
}